// Round 23
// baseline (1013.067 us; speedup 1.0000x reference)
//
#include <hip/hip_runtime.h>
#include <hip/hip_bf16.h>
#include <cstdint>

#define T_STEPS 24

typedef __attribute__((ext_vector_type(8))) short bf16x8;
typedef __attribute__((ext_vector_type(4))) float f32x4;
typedef __attribute__((ext_vector_type(16))) float f32x16;

__device__ __forceinline__ float bcast(float v, int lane) {
    return __int_as_float(__builtin_amdgcn_readlane(__float_as_int(v), lane));
}
__device__ __forceinline__ float frcp(float x) {
    return __builtin_amdgcn_rcpf(x);
}
__device__ __forceinline__ float sigm(float x) {
    return frcp(1.f + __expf(-x));
}
__device__ __forceinline__ float tanh_(float x) {
    float t = __expf(2.f * x);
    return 1.f - 2.f * frcp(t + 1.f);
}
__device__ __forceinline__ ushort bf_rne(float v) {
    unsigned u = __float_as_uint(v);
    u += 0x7FFFu + ((u >> 16) & 1u);
    return (ushort)(u >> 16);
}
__device__ __forceinline__ float bf_dec(ushort h) {
    return __uint_as_float(((unsigned)h) << 16);
}

// ---- Prep: 16x16x32-layout W_hh-hi tiles + augment (W_ih|bias); zero stats.
__global__ void lstm_prep_kernel(const float* __restrict__ W_hh,
                                 const float* __restrict__ W_ih,
                                 const float* __restrict__ b_ih,
                                 const float* __restrict__ b_hh,
                                 ushort* __restrict__ wf,
                                 double* __restrict__ stats) {
    int idx = blockIdx.x * 256 + threadIdx.x;
    if (idx < 2048) {
        int l = idx & 63, tile = idx >> 6;
        int kf = tile & 1, gcc = tile >> 1;
        int g = gcc >> 2, cc = gcc & 3;
        int out = g * 64 + cc * 16 + (l & 15);
        int k0 = kf * 32 + (l >> 4) * 8;
        ushort* d = wf + idx * 8;
        for (int j = 0; j < 8; ++j)
            d[j] = bf_rne(W_hh[out * 64 + k0 + j]);
    } else if (idx < 2048 + 1024) {
        int i2 = idx - 2048;
        int l = i2 & 63, tile = i2 >> 6;
        int g = tile >> 2, cc = tile & 3;
        ushort* d = wf + 16384 + i2 * 8;
        ushort v[8] = {0, 0, 0, 0, 0, 0, 0, 0};
        if (l < 16) {
            int gate = g * 64 + cc * 16 + l;
            float w0 = W_ih[gate * 2 + 0], w1 = W_ih[gate * 2 + 1];
            float b = b_ih[gate] + b_hh[gate];
            ushort w0h = bf_rne(w0), w1h = bf_rne(w1);
            v[0] = w0h; v[1] = w1h; v[2] = bf_rne(b);
            v[3] = w0h; v[4] = w1h;
            v[5] = bf_rne(w0 - bf_dec(w0h));
            v[6] = bf_rne(w1 - bf_dec(w1h));
        }
        for (int j = 0; j < 8; ++j) d[j] = v[j];
    } else if (idx < 2048 + 1024 + 640) {
        stats[idx - 3072] = 0.0;
    }
}

// ---- Prep2: frag tables for GAT W (hi/lo), FC1 slices (hi/lo), va = W@a, weae
__global__ void prep2_kernel(const float* __restrict__ W_gat,
                             const float* __restrict__ att_src,
                             const float* __restrict__ att_dst,
                             const float* __restrict__ W_edge,
                             const float* __restrict__ att_edge,
                             const float* __restrict__ W_fc1,
                             ushort* __restrict__ gw, ushort* __restrict__ gf,
                             float* __restrict__ va, float* __restrict__ weae) {
    int idx = blockIdx.x * 256 + threadIdx.x;
    if (idx < 5120) {
        int layer = idx >> 10;
        int e = idx & 1023;
        int which = e >> 9;
        int fe = e & 511;
        int f = fe >> 6, l = fe & 63;
        int cb = f >> 2, c = f & 3;
        int col = cb * 32 + (l & 31);
        int k0 = c * 16 + (l >> 5) * 8;
        ushort* dst = (which ? gf : gw) + layer * 8192 + fe * 8;
        for (int j = 0; j < 8; ++j) {
            int k = k0 + j;
            float v = which ? W_fc1[col * 320 + layer * 64 + k]
                            : W_gat[layer * 4096 + k * 64 + col];
            ushort hh = bf_rne(v);
            dst[j] = hh;
            dst[j + 4096] = bf_rne(v - bf_dec(hh));
        }
    } else if (idx < 5120 + 640) {
        int i2 = idx - 5120;
        int layer = i2 >> 7, kk = i2 & 127;
        int which = kk >> 6, k = kk & 63;
        const float* a = (which ? att_dst : att_src) + layer * 64;
        float s = 0.f;
        for (int col = 0; col < 64; ++col) s += W_gat[layer * 4096 + k * 64 + col] * a[col];
        va[layer * 128 + which * 64 + k] = s;
    } else if (idx < 5120 + 640 + 10) {
        int i2 = idx - 5120 - 640;
        int layer = i2 >> 1, d = i2 & 1;
        float s = 0.f;
        for (int j = 0; j < 64; ++j) s += W_edge[layer * 128 + d * 64 + j] * att_edge[layer * 64 + j];
        weae[layer * 2 + d] = s;
    }
}

// ---- MFMA LSTM v4 (R22 + c_regs index FIX): 512-thr = 8 waves x 64 nodes.
// B-frags read once per cc, reused across 4 node-tiles (LDS reads/t 4x down).
// R22 BUG: ci used (l>>4) [thread-constant] instead of cc -> channel groups
// aliased the same cell state. Fixed: ci = nb*16 + cc*4 + j.
__global__ __launch_bounds__(512, 2) void lstm_kernel(
        const float* __restrict__ x, const ushort* __restrict__ wf,
        float* __restrict__ h_out, float* __restrict__ fc1acc, int N) {
    extern __shared__ char smem[];
    int tid = threadIdx.x;
    {
        const uint4* src = (const uint4*)wf;
        uint4* dst = (uint4*)smem;
        for (int i = tid; i < 3072; i += 512) dst[i] = src[i];
    }
    __syncthreads();
    int l = tid & 63, wave = tid >> 6;
    int n0 = (blockIdx.x * 8 + wave) * 64;
    if (n0 >= N) return;
    char* hmem = smem + 49152 + wave * 8192;  // [64 rows][64 ch] bf16, XOR-swz
    for (int i = l; i < 2048; i += 64) ((unsigned*)hmem)[i] = 0u;

    float c_regs[64];
#pragma unroll
    for (int i = 0; i < 64; ++i) c_regs[i] = 0.f;

    const int arow = l & 15;
    const int aq = l >> 4;

    for (int t = 0; t < T_STEPS; ++t) {
        bf16x8 a2[4];
#pragma unroll
        for (int nb = 0; nb < 4; ++nb) {
            bf16x8 v = {};
            if (l < 16) {
                int node = n0 + nb * 16 + l;
                float x0 = 0.f, x1 = 0.f;
                if (node < N) {
                    float2 xv = *(const float2*)(x + ((size_t)node * T_STEPS + t) * 2);
                    x0 = xv.x; x1 = xv.y;
                }
                ushort x0h = bf_rne(x0), x1h = bf_rne(x1);
                v[0] = (short)x0h; v[1] = (short)x1h; v[2] = (short)0x3F80;
                v[3] = (short)bf_rne(x0 - bf_dec(x0h));
                v[4] = (short)bf_rne(x1 - bf_dec(x1h));
                v[5] = (short)x0h; v[6] = (short)x1h; v[7] = 0;
            }
            a2[nb] = v;
        }
        bf16x8 ah[4][2];
#pragma unroll
        for (int nb = 0; nb < 4; ++nb)
#pragma unroll
            for (int kf = 0; kf < 2; ++kf) {
                int row = nb * 16 + arow;
                unsigned blk = (unsigned)(kf * 4 + aq);
                unsigned addr = (unsigned)(row * 128) + ((blk ^ (unsigned)(row & 7)) << 4);
                ah[nb][kf] = *(const bf16x8*)(hmem + addr);
            }
#pragma unroll
        for (int cc = 0; cc < 4; ++cc) {
            bf16x8 b2r[4], bhr[2][4];
#pragma unroll
            for (int g = 0; g < 4; ++g)
                b2r[g] = *(const bf16x8*)(smem + 32768 + ((g * 4 + cc) * 64 + l) * 16);
#pragma unroll
            for (int kf = 0; kf < 2; ++kf)
#pragma unroll
                for (int g = 0; g < 4; ++g)
                    bhr[kf][g] = *(const bf16x8*)(smem + (((g * 4 + cc) * 2 + kf) * 64 + l) * 16);
#pragma unroll
            for (int nb = 0; nb < 4; ++nb) {
                f32x4 acc[4];
#pragma unroll
                for (int g = 0; g < 4; ++g) {
                    f32x4 z = {};
                    acc[g] = __builtin_amdgcn_mfma_f32_16x16x32_bf16(a2[nb], b2r[g], z, 0, 0, 0);
                }
#pragma unroll
                for (int kf = 0; kf < 2; ++kf)
#pragma unroll
                    for (int g = 0; g < 4; ++g)
                        acc[g] = __builtin_amdgcn_mfma_f32_16x16x32_bf16(ah[nb][kf], bhr[kf][g], acc[g], 0, 0, 0);
#pragma unroll
                for (int j = 0; j < 4; ++j) {
                    float iv = acc[0][j], fv = acc[1][j], gv = acc[2][j], ov = acc[3][j];
                    int ci = nb * 16 + cc * 4 + j;  // FIXED (was (l>>4), aliased)
                    float co = c_regs[ci];
                    float cn = sigm(fv) * co + sigm(iv) * tanh_(gv);
                    float hn = sigm(ov) * tanh_(cn);
                    c_regs[ci] = cn;
                    int row = nb * 16 + (l >> 4) * 4 + j;
                    int ch = cc * 16 + (l & 15);
                    unsigned blk = (unsigned)(ch >> 3);
                    unsigned addr = (unsigned)(row * 128) + ((blk ^ (unsigned)(row & 7)) << 4) + (ch & 7) * 2;
                    *(ushort*)(hmem + addr) = bf_rne(hn);
                }
            }
        }
    }
    // write h (decode bf16) + zero fc1acc: two row-halves
#pragma unroll
    for (int rr = 0; rr < 2; ++rr) {
        int row = rr * 32 + (l >> 1), chb = (l & 1) * 32;
        int node = n0 + row;
        if (node < N) {
#pragma unroll
            for (int q = 0; q < 4; ++q) {
                unsigned blk = (unsigned)((l & 1) * 4 + q);
                unsigned addr = (unsigned)(row * 128) + ((blk ^ (unsigned)(row & 7)) << 4);
                uint4 p = *(const uint4*)(hmem + addr);
                float4 v0, v1;
                v0.x = bf_dec((ushort)(p.x & 0xffff)); v0.y = bf_dec((ushort)(p.x >> 16));
                v0.z = bf_dec((ushort)(p.y & 0xffff)); v0.w = bf_dec((ushort)(p.y >> 16));
                v1.x = bf_dec((ushort)(p.z & 0xffff)); v1.y = bf_dec((ushort)(p.z >> 16));
                v1.z = bf_dec((ushort)(p.w & 0xffff)); v1.w = bf_dec((ushort)(p.w >> 16));
                *(float4*)(h_out + (size_t)node * 64 + chb + q * 8) = v0;
                *(float4*)(h_out + (size_t)node * 64 + chb + q * 8 + 4) = v1;
                float4 zz = {0.f, 0.f, 0.f, 0.f};
                *(float4*)(fc1acc + (size_t)node * 64 + chb + q * 8) = zz;
                *(float4*)(fc1acc + (size_t)node * 64 + chb + q * 8 + 4) = zz;
            }
        }
    }
}

// ---------------- CSR build (dst-bucketed), once per call ----------------
__global__ void csr_zero_kernel(int* __restrict__ deg, int N) {
    int i = blockIdx.x * 256 + threadIdx.x;
    if (i < N) deg[i] = 0;
}
__global__ void csr_hist_kernel(const int* __restrict__ ei, int* __restrict__ deg, int E) {
    int e = blockIdx.x * 256 + threadIdx.x;
    if (e < E) atomicAdd(&deg[ei[E + e]], 1);
}
__global__ void csr_scan1_kernel(const int* __restrict__ deg, int* __restrict__ rowptr,
                                 int* __restrict__ bsum, int N) {
    __shared__ int sh[256];
    int tid = threadIdx.x;
    int base = blockIdx.x * 1024 + tid * 4;
    int d0 = base + 0 < N ? deg[base + 0] : 0;
    int d1 = base + 1 < N ? deg[base + 1] : 0;
    int d2 = base + 2 < N ? deg[base + 2] : 0;
    int d3 = base + 3 < N ? deg[base + 3] : 0;
    int tsum = d0 + d1 + d2 + d3;
    sh[tid] = tsum;
    __syncthreads();
    for (int off = 1; off < 256; off <<= 1) {
        int v = 0;
        if (tid >= off) v = sh[tid - off];
        __syncthreads();
        if (tid >= off) sh[tid] += v;
        __syncthreads();
    }
    int excl = sh[tid] - tsum;
    if (base + 0 < N) rowptr[base + 0] = excl;
    if (base + 1 < N) rowptr[base + 1] = excl + d0;
    if (base + 2 < N) rowptr[base + 2] = excl + d0 + d1;
    if (base + 3 < N) rowptr[base + 3] = excl + d0 + d1 + d2;
    if (tid == 255) bsum[blockIdx.x] = sh[255];
}
__global__ void csr_scan2_kernel(int* __restrict__ bsum, int* __restrict__ rowptr,
                                 int nb, int N) {
    if (threadIdx.x == 0 && blockIdx.x == 0) {
        int running = 0;
        for (int b = 0; b < nb; ++b) {
            int t = bsum[b];
            bsum[b] = running;
            running += t;
        }
        rowptr[N] = running;
    }
}
__global__ void csr_scan3_kernel(int* __restrict__ rowptr, int* __restrict__ cursor,
                                 const int* __restrict__ bsum, int N) {
    int tid = threadIdx.x;
    int base = blockIdx.x * 1024 + tid * 4;
    int ofs = bsum[blockIdx.x];
#pragma unroll
    for (int j = 0; j < 4; ++j) {
        if (base + j < N) {
            int v = rowptr[base + j] + ofs;
            rowptr[base + j] = v;
            cursor[base + j] = v;
        }
    }
}
__global__ void csr_scatter_kernel(const int* __restrict__ ei, const float* __restrict__ ea,
                                   int* __restrict__ cursor,
                                   int* __restrict__ csr_src, float* __restrict__ csr_ea,
                                   int E) {
    int e = blockIdx.x * 256 + threadIdx.x;
    if (e >= E) return;
    int s = ei[e], d = ei[E + e];
    int pos = atomicAdd(&cursor[d], 1);
    csr_src[pos] = s;
    *(float2*)(csr_ea + (size_t)pos * 2) = *(const float2*)(ea + (size_t)e * 2);
}

// ---- GAT scores (layer 0): hs(bf16) = h@W via MFMA; asrc/adst = h.(W@a).
__global__ __launch_bounds__(256, 4) void gat_scores_kernel(
        const float* __restrict__ h, const ushort* __restrict__ gfrag,
        const float* __restrict__ va, ushort* __restrict__ hs,
        float* __restrict__ asrc, float* __restrict__ adst, int N) {
    int tid = threadIdx.x;
    int l = tid & 63, wave = tid >> 6;
    int n0 = (blockIdx.x * 4 + wave) * 32;
    if (n0 >= N) return;
    const int row_a = l & 31, kg = (l >> 5) * 8;
    bool valid = (n0 + row_a) < N;
    const float* hrow = h + (size_t)(n0 + row_a) * 64;
    bf16x8 ahi[4], alo[4];
    float ps = 0.f, pd = 0.f;
#pragma unroll
    for (int c = 0; c < 4; ++c) {
        float hv[8];
        if (valid) {
            float4 v0 = *(const float4*)(hrow + c * 16 + kg);
            float4 v1 = *(const float4*)(hrow + c * 16 + kg + 4);
            hv[0] = v0.x; hv[1] = v0.y; hv[2] = v0.z; hv[3] = v0.w;
            hv[4] = v1.x; hv[5] = v1.y; hv[6] = v1.z; hv[7] = v1.w;
        } else {
#pragma unroll
            for (int j = 0; j < 8; ++j) hv[j] = 0.f;
        }
#pragma unroll
        for (int j = 0; j < 8; ++j) {
            ps += hv[j] * va[c * 16 + kg + j];
            pd += hv[j] * va[64 + c * 16 + kg + j];
            ushort hb = bf_rne(hv[j]);
            ahi[c][j] = (short)hb;
            alo[c][j] = (short)bf_rne(hv[j] - bf_dec(hb));
        }
    }
    ps += __shfl_xor(ps, 32, 64);
    pd += __shfl_xor(pd, 32, 64);
    if (l < 32 && valid) { asrc[n0 + l] = ps; adst[n0 + l] = pd; }
#pragma unroll
    for (int cb = 0; cb < 2; ++cb) {
        f32x16 acc = {};
#pragma unroll
        for (int c = 0; c < 4; ++c) {
            const ushort* bp = gfrag + (size_t)(((cb * 4 + c) * 64 + l) * 8);
            bf16x8 bhi = *(const bf16x8*)bp;
            bf16x8 blo = *(const bf16x8*)(bp + 4096);
            acc = __builtin_amdgcn_mfma_f32_32x32x16_bf16(ahi[c], bhi, acc, 0, 0, 0);
            acc = __builtin_amdgcn_mfma_f32_32x32x16_bf16(alo[c], bhi, acc, 0, 0, 0);
            acc = __builtin_amdgcn_mfma_f32_32x32x16_bf16(ahi[c], blo, acc, 0, 0, 0);
        }
#pragma unroll
        for (int r = 0; r < 16; ++r) {
            int row = (r & 3) + 8 * (r >> 2) + 4 * (l >> 5);
            int node = n0 + row;
            if (node < N) hs[(size_t)node * 64 + cb * 32 + (l & 31)] = bf_rne(acc[r]);
        }
    }
}

// ---- Fused per-dst edge kernel: persistent grid-stride (R20-proven).
__global__ void gat_edge_kernel(const int* __restrict__ rowptr,
                                const int* __restrict__ csr_src,
                                const float* __restrict__ csr_ea,
                                const float* __restrict__ asrc,
                                const float* __restrict__ adst,
                                const float* __restrict__ weae,
                                const ushort* __restrict__ hs,
                                const float* __restrict__ bias,
                                float* __restrict__ go,
                                double* __restrict__ stats, int N) {
    int tid = threadIdx.x;
    int lane = tid & 63, wave = tid >> 6;
    int stride = gridDim.x * 4;
    float bl = bias[lane];
    float w0 = weae[0], w1 = weae[1];
    double sAcc = 0.0, ssAcc = 0.0;
    for (int d = blockIdx.x * 4 + wave; d < N; d += stride) {
        float acc = bl;
        int start = rowptr[d], deg = rowptr[d + 1] - start;
        float ad = adst[d];
        if (deg > 0 && deg <= 64) {
            int s = 0;
            float a = -1e30f;
            if (lane < deg) {
                s = csr_src[start + lane];
                float2 eav = *(const float2*)(csr_ea + (size_t)(start + lane) * 2);
                a = asrc[s] + ad + eav.x * w0 + eav.y * w1;
                a = a > 0.f ? a : 0.2f * a;
            }
            float m = a;
            for (int mm = 32; mm; mm >>= 1) m = fmaxf(m, __shfl_xor(m, mm, 64));
            float ex = lane < deg ? __expf(a - m) : 0.f;
            float den = ex;
            for (int mm = 32; mm; mm >>= 1) den += __shfl_xor(den, mm, 64);
            float w = ex * frcp(den + 1e-16f);
            for (int j = 0; j < deg; ++j) {
                int sj = __builtin_amdgcn_readlane(s, j);
                float wj = bcast(w, j);
                acc += wj * bf_dec(hs[(size_t)sj * 64 + lane]);
            }
        } else if (deg > 64) {
            float m = -1e30f;
            for (int c0 = 0; c0 < deg; c0 += 64) {
                float a = -1e30f;
                if (c0 + lane < deg) {
                    int s2 = csr_src[start + c0 + lane];
                    float2 eav = *(const float2*)(csr_ea + (size_t)(start + c0 + lane) * 2);
                    a = asrc[s2] + ad + eav.x * w0 + eav.y * w1;
                    a = a > 0.f ? a : 0.2f * a;
                }
                for (int mm = 32; mm; mm >>= 1) a = fmaxf(a, __shfl_xor(a, mm, 64));
                m = fmaxf(m, a);
            }
            float den = 0.f;
            for (int c0 = 0; c0 < deg; c0 += 64) {
                float a = -1e30f;
                if (c0 + lane < deg) {
                    int s2 = csr_src[start + c0 + lane];
                    float2 eav = *(const float2*)(csr_ea + (size_t)(start + c0 + lane) * 2);
                    a = asrc[s2] + ad + eav.x * w0 + eav.y * w1;
                    a = a > 0.f ? a : 0.2f * a;
                }
                float ex = (c0 + lane < deg) ? __expf(a - m) : 0.f;
                for (int mm = 32; mm; mm >>= 1) ex += __shfl_xor(ex, mm, 64);
                den += ex;
            }
            for (int c0 = 0; c0 < deg; c0 += 64) {
                int s2 = 0;
                float a = -1e30f;
                if (c0 + lane < deg) {
                    s2 = csr_src[start + c0 + lane];
                    float2 eav = *(const float2*)(csr_ea + (size_t)(start + c0 + lane) * 2);
                    a = asrc[s2] + ad + eav.x * w0 + eav.y * w1;
                    a = a > 0.f ? a : 0.2f * a;
                }
                float w = ((c0 + lane < deg) ? __expf(a - m) : 0.f) * frcp(den + 1e-16f);
                int cnt = deg - c0 < 64 ? deg - c0 : 64;
                for (int j = 0; j < cnt; ++j) {
                    int sj = __builtin_amdgcn_readlane(s2, j);
                    float wj = bcast(w, j);
                    acc += wj * bf_dec(hs[(size_t)sj * 64 + lane]);
                }
            }
        }
        go[(size_t)d * 64 + lane] = acc;
        sAcc += (double)acc;
        ssAcc += (double)acc * acc;
    }
    for (int mm = 32; mm; mm >>= 1) { sAcc += __shfl_xor(sAcc, mm, 64); ssAcc += __shfl_xor(ssAcc, mm, 64); }
    __shared__ double sh[8];
    if (lane == 0) { sh[wave * 2] = sAcc; sh[wave * 2 + 1] = ssAcc; }
    __syncthreads();
    if (tid == 0) {
        double ts = 0, tss = 0;
        for (int w2 = 0; w2 < 4; ++w2) { ts += sh[w2 * 2]; tss += sh[w2 * 2 + 1]; }
        double* slot = stats + (blockIdx.x & 63) * 2;
        unsafeAtomicAdd(&slot[0], ts);
        unsafeAtomicAdd(&slot[1], tss);
    }
}

// ---- Fused: LN(graph)+ReLU -> v; fc1acc += v@W_fc1_slice^T (MFMA);
//      and (if do_next) next layer's hs(bf16) = v@W_gat, asrc/adst = v.(W@a).
__global__ __launch_bounds__(256, 4) void ln_apply_kernel(
        const float* __restrict__ go, const double* __restrict__ stats,
        const float* __restrict__ g, const float* __restrict__ b,
        const ushort* __restrict__ ffrag, const ushort* __restrict__ gwnext,
        const float* __restrict__ vanext,
        float* __restrict__ fc1acc, ushort* __restrict__ hs,
        float* __restrict__ asrc, float* __restrict__ adst,
        int N, int do_next) {
    int tid = threadIdx.x;
    int l = tid & 63, wave = tid >> 6;
    double sA = stats[l * 2], sB = stats[l * 2 + 1];
    for (int mm = 32; mm; mm >>= 1) { sA += __shfl_xor(sA, mm, 64); sB += __shfl_xor(sB, mm, 64); }
    double M = (double)N * 64.0;
    double mu = sA / M;
    float mean = (float)mu;
    float var = (float)(sB / M - mu * mu);
    float inv = 1.f / (sqrtf(fmaxf(var, 0.f)) + 1e-5f);
    int n0 = (blockIdx.x * 4 + wave) * 32;
    if (n0 >= N) return;
    const int row_a = l & 31, kg = (l >> 5) * 8;
    bool valid = (n0 + row_a) < N;
    const float* gorow = go + (size_t)(n0 + row_a) * 64;
    bf16x8 ahi[4], alo[4];
    float ps = 0.f, pd = 0.f;
#pragma unroll
    for (int c = 0; c < 4; ++c) {
        int ch0 = c * 16 + kg;
        float4 g0 = *(const float4*)(g + ch0);
        float4 g1 = *(const float4*)(g + ch0 + 4);
        float4 b0 = *(const float4*)(b + ch0);
        float4 b1 = *(const float4*)(b + ch0 + 4);
        float gl[8] = {g0.x, g0.y, g0.z, g0.w, g1.x, g1.y, g1.z, g1.w};
        float bl[8] = {b0.x, b0.y, b0.z, b0.w, b1.x, b1.y, b1.z, b1.w};
        float hv[8];
        if (valid) {
            float4 v0 = *(const float4*)(gorow + ch0);
            float4 v1 = *(const float4*)(gorow + ch0 + 4);
            hv[0] = v0.x; hv[1] = v0.y; hv[2] = v0.z; hv[3] = v0.w;
            hv[4] = v1.x; hv[5] = v1.y; hv[6] = v1.z; hv[7] = v1.w;
        } else {
#pragma unroll
            for (int j = 0; j < 8; ++j) hv[j] = 0.f;
        }
#pragma unroll
        for (int j = 0; j < 8; ++j) {
            float v = fmaxf((hv[j] - mean) * inv * gl[j] + bl[j], 0.f);
            ps += v * vanext[c * 16 + kg + j];
            pd += v * vanext[64 + c * 16 + kg + j];
            ushort hb = bf_rne(v);
            ahi[c][j] = (short)hb;
            alo[c][j] = (short)bf_rne(v - bf_dec(hb));
        }
    }
#pragma unroll
    for (int cb = 0; cb < 2; ++cb) {
        f32x16 acc = {};
#pragma unroll
        for (int c = 0; c < 4; ++c) {
            const ushort* bp = ffrag + (size_t)(((cb * 4 + c) * 64 + l) * 8);
            bf16x8 bhi = *(const bf16x8*)bp;
            bf16x8 blo = *(const bf16x8*)(bp + 4096);
            acc = __builtin_amdgcn_mfma_f32_32x32x16_bf16(ahi[c], bhi, acc, 0, 0, 0);
            acc = __builtin_amdgcn_mfma_f32_32x32x16_bf16(alo[c], bhi, acc, 0, 0, 0);
            acc = __builtin_amdgcn_mfma_f32_32x32x16_bf16(ahi[c], blo, acc, 0, 0, 0);
        }
#pragma unroll
        for (int r = 0; r < 16; ++r) {
            int row = (r & 3) + 8 * (r >> 2) + 4 * (l >> 5);
            int node = n0 + row;
            if (node < N) fc1acc[(size_t)node * 64 + cb * 32 + (l & 31)] += acc[r];
        }
    }
    if (do_next) {
        ps += __shfl_xor(ps, 32, 64);
        pd += __shfl_xor(pd, 32, 64);
        if (l < 32 && valid) { asrc[n0 + l] = ps; adst[n0 + l] = pd; }
#pragma unroll
        for (int cb = 0; cb < 2; ++cb) {
            f32x16 acc = {};
#pragma unroll
            for (int c = 0; c < 4; ++c) {
                const ushort* bp = gwnext + (size_t)(((cb * 4 + c) * 64 + l) * 8);
                bf16x8 bhi = *(const bf16x8*)bp;
                bf16x8 blo = *(const bf16x8*)(bp + 4096);
                acc = __builtin_amdgcn_mfma_f32_32x32x16_bf16(ahi[c], bhi, acc, 0, 0, 0);
                acc = __builtin_amdgcn_mfma_f32_32x32x16_bf16(alo[c], bhi, acc, 0, 0, 0);
                acc = __builtin_amdgcn_mfma_f32_32x32x16_bf16(ahi[c], blo, acc, 0, 0, 0);
            }
#pragma unroll
            for (int r = 0; r < 16; ++r) {
                int row = (r & 3) + 8 * (r >> 2) + 4 * (l >> 5);
                int node = n0 + row;
                if (node < N) hs[(size_t)node * 64 + cb * 32 + (l & 31)] = bf_rne(acc[r]);
            }
        }
    }
}

__global__ void head_kernel(const float* __restrict__ fc1acc, const float* __restrict__ b1,
                            const float* __restrict__ W2, const float* __restrict__ b2,
                            float* __restrict__ out, int N) {
    int lane = threadIdx.x & 63, wave = threadIdx.x >> 6;
    int n = blockIdx.x * 4 + wave;
    if (n >= N) return;
    float v = fmaxf(fc1acc[n * 64 + lane] + b1[lane], 0.f);
    float r0 = v * W2[lane];
    float r1 = v * W2[64 + lane];
    for (int m = 32; m; m >>= 1) { r0 += __shfl_xor(r0, m, 64); r1 += __shfl_xor(r1, m, 64); }
    if (lane == 0) { out[n * 2 + 0] = r0 + b2[0]; out[n * 2 + 1] = r1 + b2[1]; }
}

extern "C" void kernel_launch(void* const* d_in, const int* in_sizes, int n_in,
                              void* d_out, int out_size, void* d_ws, size_t ws_size,
                              hipStream_t stream) {
    const float* x        = (const float*)d_in[0];
    const int*   ei       = (const int*)d_in[1];
    const float* ea       = (const float*)d_in[2];
    const float* W_ih     = (const float*)d_in[3];
    const float* W_hh     = (const float*)d_in[4];
    const float* b_ih     = (const float*)d_in[5];
    const float* b_hh     = (const float*)d_in[6];
    const float* W_gat    = (const float*)d_in[7];
    const float* att_src  = (const float*)d_in[8];
    const float* att_dst  = (const float*)d_in[9];
    const float* W_edge   = (const float*)d_in[10];
    const float* att_edge = (const float*)d_in[11];
    const float* b_gat    = (const float*)d_in[12];
    const float* ln_g     = (const float*)d_in[13];
    const float* ln_b     = (const float*)d_in[14];
    const float* W_fc1    = (const float*)d_in[15];
    const float* b_fc1    = (const float*)d_in[16];
    const float* W_fc2    = (const float*)d_in[17];
    const float* b_fc2    = (const float*)d_in[18];
    float* out = (float*)d_out;

    int N = in_sizes[0] / (T_STEPS * 2);
    int E = in_sizes[1] / 2;
    size_t N64 = (size_t)N * 64;

    float* ws   = (float*)d_ws;
    float* h    = ws;
    ushort* hs  = (ushort*)(h + N64);               // N64 bf16
    float* go   = (float*)(hs + N64);
    float* fc1  = go + N64;
    float* asrc = fc1 + N64;
    float* adst = asrc + N;
    float* va_all   = adst + N;                     // 640
    float* weae_all = va_all + 640;                 // 10
    double* stats = (double*)(((uintptr_t)(weae_all + 10) + 15) & ~(uintptr_t)15);  // 640
    ushort* wfrag = (ushort*)(stats + 640);         // 24576
    ushort* gw    = wfrag + 24576;                  // 40960
    ushort* gf    = gw + 40960;                     // 40960
    int* deg     = (int*)(gf + 40960);
    int* rowptr  = deg + N;                          // N+1
    int* cursor  = rowptr + N + 1;
    int* bsum    = cursor + N;                       // <=128
    int* csr_src = bsum + 128;                       // E
    float* csr_ea = (float*)(((uintptr_t)(csr_src + E) + 15) & ~(uintptr_t)15);  // 2E

    int nb = (N + 1023) / 1024;
    int tiles64 = (N + 63) / 64;

    lstm_prep_kernel<<<15, 256, 0, stream>>>(W_hh, W_ih, b_ih, b_hh, wfrag, stats);
    prep2_kernel<<<23, 256, 0, stream>>>(W_gat, att_src, att_dst, W_edge, att_edge,
                                         W_fc1, gw, gf, va_all, weae_all);
    lstm_kernel<<<(tiles64 + 7) / 8, 512, 114688, stream>>>(x, wfrag, h, fc1, N);

    csr_zero_kernel<<<(N + 255) / 256, 256, 0, stream>>>(deg, N);
    csr_hist_kernel<<<(E + 255) / 256, 256, 0, stream>>>(ei, deg, E);
    csr_scan1_kernel<<<nb, 256, 0, stream>>>(deg, rowptr, bsum, N);
    csr_scan2_kernel<<<1, 64, 0, stream>>>(bsum, rowptr, nb, N);
    csr_scan3_kernel<<<nb, 256, 0, stream>>>(rowptr, cursor, bsum, N);
    csr_scatter_kernel<<<(E + 255) / 256, 256, 0, stream>>>(ei, ea, cursor, csr_src, csr_ea, E);

    gat_scores_kernel<<<(N + 127) / 128, 256, 0, stream>>>(h, gw, va_all, hs, asrc, adst, N);

    for (int l = 0; l < 5; ++l) {
        int nl = l + 1 < 5 ? l + 1 : 4;
        gat_edge_kernel<<<2048, 256, 0, stream>>>(
            rowptr, csr_src, csr_ea, asrc, adst, weae_all + l * 2, hs, b_gat + l * 64,
            go, stats + l * 128, N);
        ln_apply_kernel<<<(N + 127) / 128, 256, 0, stream>>>(
            go, stats + l * 128, ln_g + l * 64, ln_b + l * 64, gf + l * 8192,
            gw + nl * 8192, va_all + nl * 128, fc1, hs, asrc, adst, N, l < 4 ? 1 : 0);
    }
    head_kernel<<<(N + 3) / 4, 256, 0, stream>>>(fc1, b_fc1, W_fc2, b_fc2, out, N);
}

// Round 24
// 1000.391 us; speedup vs baseline: 1.0127x; 1.0127x over previous
//
#include <hip/hip_runtime.h>
#include <hip/hip_bf16.h>
#include <cstdint>

#define T_STEPS 24

typedef __attribute__((ext_vector_type(8))) short bf16x8;
typedef __attribute__((ext_vector_type(4))) float f32x4;
typedef __attribute__((ext_vector_type(16))) float f32x16;

__device__ __forceinline__ float bcast(float v, int lane) {
    return __int_as_float(__builtin_amdgcn_readlane(__float_as_int(v), lane));
}
__device__ __forceinline__ float frcp(float x) {
    return __builtin_amdgcn_rcpf(x);
}
__device__ __forceinline__ float sigm(float x) {
    return frcp(1.f + __expf(-x));
}
__device__ __forceinline__ float tanh_(float x) {
    float t = __expf(2.f * x);
    return 1.f - 2.f * frcp(t + 1.f);
}
__device__ __forceinline__ ushort bf_rne(float v) {
    unsigned u = __float_as_uint(v);
    u += 0x7FFFu + ((u >> 16) & 1u);
    return (ushort)(u >> 16);
}
__device__ __forceinline__ float bf_dec(ushort h) {
    return __uint_as_float(((unsigned)h) << 16);
}

// ---- Prep: 16x16x32-layout W_hh-hi tiles + augment (W_ih|bias); zero stats.
__global__ void lstm_prep_kernel(const float* __restrict__ W_hh,
                                 const float* __restrict__ W_ih,
                                 const float* __restrict__ b_ih,
                                 const float* __restrict__ b_hh,
                                 ushort* __restrict__ wf,
                                 double* __restrict__ stats) {
    int idx = blockIdx.x * 256 + threadIdx.x;
    if (idx < 2048) {
        int l = idx & 63, tile = idx >> 6;
        int kf = tile & 1, gcc = tile >> 1;
        int g = gcc >> 2, cc = gcc & 3;
        int out = g * 64 + cc * 16 + (l & 15);
        int k0 = kf * 32 + (l >> 4) * 8;
        ushort* d = wf + idx * 8;
        for (int j = 0; j < 8; ++j)
            d[j] = bf_rne(W_hh[out * 64 + k0 + j]);
    } else if (idx < 2048 + 1024) {
        int i2 = idx - 2048;
        int l = i2 & 63, tile = i2 >> 6;
        int g = tile >> 2, cc = tile & 3;
        ushort* d = wf + 16384 + i2 * 8;
        ushort v[8] = {0, 0, 0, 0, 0, 0, 0, 0};
        if (l < 16) {
            int gate = g * 64 + cc * 16 + l;
            float w0 = W_ih[gate * 2 + 0], w1 = W_ih[gate * 2 + 1];
            float b = b_ih[gate] + b_hh[gate];
            ushort w0h = bf_rne(w0), w1h = bf_rne(w1);
            v[0] = w0h; v[1] = w1h; v[2] = bf_rne(b);
            v[3] = w0h; v[4] = w1h;
            v[5] = bf_rne(w0 - bf_dec(w0h));
            v[6] = bf_rne(w1 - bf_dec(w1h));
        }
        for (int j = 0; j < 8; ++j) d[j] = v[j];
    } else if (idx < 2048 + 1024 + 640) {
        stats[idx - 3072] = 0.0;
    }
}

// ---- Prep2: frag tables for GAT W (hi/lo), FC1 slices (hi/lo), va = W@a, weae
__global__ void prep2_kernel(const float* __restrict__ W_gat,
                             const float* __restrict__ att_src,
                             const float* __restrict__ att_dst,
                             const float* __restrict__ W_edge,
                             const float* __restrict__ att_edge,
                             const float* __restrict__ W_fc1,
                             ushort* __restrict__ gw, ushort* __restrict__ gf,
                             float* __restrict__ va, float* __restrict__ weae) {
    int idx = blockIdx.x * 256 + threadIdx.x;
    if (idx < 5120) {
        int layer = idx >> 10;
        int e = idx & 1023;
        int which = e >> 9;
        int fe = e & 511;
        int f = fe >> 6, l = fe & 63;
        int cb = f >> 2, c = f & 3;
        int col = cb * 32 + (l & 31);
        int k0 = c * 16 + (l >> 5) * 8;
        ushort* dst = (which ? gf : gw) + layer * 8192 + fe * 8;
        for (int j = 0; j < 8; ++j) {
            int k = k0 + j;
            float v = which ? W_fc1[col * 320 + layer * 64 + k]
                            : W_gat[layer * 4096 + k * 64 + col];
            ushort hh = bf_rne(v);
            dst[j] = hh;
            dst[j + 4096] = bf_rne(v - bf_dec(hh));
        }
    } else if (idx < 5120 + 640) {
        int i2 = idx - 5120;
        int layer = i2 >> 7, kk = i2 & 127;
        int which = kk >> 6, k = kk & 63;
        const float* a = (which ? att_dst : att_src) + layer * 64;
        float s = 0.f;
        for (int col = 0; col < 64; ++col) s += W_gat[layer * 4096 + k * 64 + col] * a[col];
        va[layer * 128 + which * 64 + k] = s;
    } else if (idx < 5120 + 640 + 10) {
        int i2 = idx - 5120 - 640;
        int layer = i2 >> 1, d = i2 & 1;
        float s = 0.f;
        for (int j = 0; j < 64; ++j) s += W_edge[layer * 128 + d * 64 + j] * att_edge[layer * 64 + j];
        weae[layer * 2 + d] = s;
    }
}

// ---- MFMA LSTM (R21 body + CU-spread tile mapping): 1024-thr, 16 waves,
// 32 nodes/wave, bf16 h tile, frcp gates, in-loop B reads.
// Mapping tile = wave*gridDim + blockIdx with grid>=256 spreads 3125 tiles
// over ALL 256 CUs (<=13 wave-tiles/CU vs 16 on 196 CUs before).
__global__ __launch_bounds__(1024, 4) void lstm_kernel(
        const float* __restrict__ x, const ushort* __restrict__ wf,
        float* __restrict__ h_out, float* __restrict__ fc1acc, int N) {
    extern __shared__ char smem[];
    int tid = threadIdx.x;
    {
        const uint4* src = (const uint4*)wf;
        uint4* dst = (uint4*)smem;
        for (int i = tid; i < 3072; i += 1024) dst[i] = src[i];
    }
    __syncthreads();
    int l = tid & 63, wave = tid >> 6;
    int tile = wave * gridDim.x + blockIdx.x;
    int n0 = tile * 32;
    if (n0 >= N) return;
    char* hmem = smem + 49152 + wave * 4096;
    for (int i = l; i < 1024; i += 64) ((unsigned*)hmem)[i] = 0u;

    float c_regs[32];
#pragma unroll
    for (int i = 0; i < 32; ++i) c_regs[i] = 0.f;

    const int arow = l & 15;
    const int aq = l >> 4;

    for (int t = 0; t < T_STEPS; ++t) {
        bf16x8 a2[2];
#pragma unroll
        for (int nb = 0; nb < 2; ++nb) {
            bf16x8 v = {};
            if (l < 16) {
                int node = n0 + nb * 16 + l;
                float x0 = 0.f, x1 = 0.f;
                if (node < N) {
                    float2 xv = *(const float2*)(x + ((size_t)node * T_STEPS + t) * 2);
                    x0 = xv.x; x1 = xv.y;
                }
                ushort x0h = bf_rne(x0), x1h = bf_rne(x1);
                v[0] = (short)x0h; v[1] = (short)x1h; v[2] = (short)0x3F80;
                v[3] = (short)bf_rne(x0 - bf_dec(x0h));
                v[4] = (short)bf_rne(x1 - bf_dec(x1h));
                v[5] = (short)x0h; v[6] = (short)x1h; v[7] = 0;
            }
            a2[nb] = v;
        }
        bf16x8 ah[2][2];
#pragma unroll
        for (int nb = 0; nb < 2; ++nb)
#pragma unroll
            for (int kf = 0; kf < 2; ++kf) {
                int row = nb * 16 + arow;
                unsigned blk = (unsigned)(kf * 4 + aq);
                unsigned addr = (unsigned)(row * 128) + ((blk ^ (unsigned)(row & 7)) << 4);
                ah[nb][kf] = *(const bf16x8*)(hmem + addr);
            }
#pragma unroll
        for (int nb = 0; nb < 2; ++nb) {
#pragma unroll
            for (int cc = 0; cc < 4; ++cc) {
                f32x4 acc[4];
#pragma unroll
                for (int g = 0; g < 4; ++g) {
                    bf16x8 b2 = *(const bf16x8*)(smem + 32768 + ((g * 4 + cc) * 64 + l) * 16);
                    f32x4 z = {};
                    acc[g] = __builtin_amdgcn_mfma_f32_16x16x32_bf16(a2[nb], b2, z, 0, 0, 0);
                }
#pragma unroll
                for (int kf = 0; kf < 2; ++kf)
#pragma unroll
                    for (int g = 0; g < 4; ++g) {
                        int tl = (g * 4 + cc) * 2 + kf;
                        bf16x8 bh = *(const bf16x8*)(smem + (tl * 64 + l) * 16);
                        acc[g] = __builtin_amdgcn_mfma_f32_16x16x32_bf16(ah[nb][kf], bh, acc[g], 0, 0, 0);
                    }
#pragma unroll
                for (int j = 0; j < 4; ++j) {
                    float iv = acc[0][j], fv = acc[1][j], gv = acc[2][j], ov = acc[3][j];
                    int ci = nb * 16 + cc * 4 + j;
                    float co = c_regs[ci];
                    float cn = sigm(fv) * co + sigm(iv) * tanh_(gv);
                    float hn = sigm(ov) * tanh_(cn);
                    c_regs[ci] = cn;
                    int row = nb * 16 + (l >> 4) * 4 + j;
                    int ch = cc * 16 + (l & 15);
                    unsigned blk = (unsigned)(ch >> 3);
                    unsigned addr = (unsigned)(row * 128) + ((blk ^ (unsigned)(row & 7)) << 4) + (ch & 7) * 2;
                    *(ushort*)(hmem + addr) = bf_rne(hn);
                }
            }
        }
    }
    int row = l >> 1, chb = (l & 1) * 32;
    int node = n0 + row;
    if (node < N) {
#pragma unroll
        for (int q = 0; q < 4; ++q) {
            unsigned blk = (unsigned)((l & 1) * 4 + q);
            unsigned addr = (unsigned)(row * 128) + ((blk ^ (unsigned)(row & 7)) << 4);
            uint4 p = *(const uint4*)(hmem + addr);
            float4 v0, v1;
            v0.x = bf_dec((ushort)(p.x & 0xffff)); v0.y = bf_dec((ushort)(p.x >> 16));
            v0.z = bf_dec((ushort)(p.y & 0xffff)); v0.w = bf_dec((ushort)(p.y >> 16));
            v1.x = bf_dec((ushort)(p.z & 0xffff)); v1.y = bf_dec((ushort)(p.z >> 16));
            v1.z = bf_dec((ushort)(p.w & 0xffff)); v1.w = bf_dec((ushort)(p.w >> 16));
            *(float4*)(h_out + (size_t)node * 64 + chb + q * 8) = v0;
            *(float4*)(h_out + (size_t)node * 64 + chb + q * 8 + 4) = v1;
            float4 zz = {0.f, 0.f, 0.f, 0.f};
            *(float4*)(fc1acc + (size_t)node * 64 + chb + q * 8) = zz;
            *(float4*)(fc1acc + (size_t)node * 64 + chb + q * 8 + 4) = zz;
        }
    }
}

// ---------------- CSR build (dst-bucketed), once per call ----------------
__global__ void csr_zero_kernel(int* __restrict__ deg, int N) {
    int i = blockIdx.x * 256 + threadIdx.x;
    if (i < N) deg[i] = 0;
}
__global__ void csr_hist_kernel(const int* __restrict__ ei, int* __restrict__ deg, int E) {
    int e = blockIdx.x * 256 + threadIdx.x;
    if (e < E) atomicAdd(&deg[ei[E + e]], 1);
}
__global__ void csr_scan1_kernel(const int* __restrict__ deg, int* __restrict__ rowptr,
                                 int* __restrict__ bsum, int N) {
    __shared__ int sh[256];
    int tid = threadIdx.x;
    int base = blockIdx.x * 1024 + tid * 4;
    int d0 = base + 0 < N ? deg[base + 0] : 0;
    int d1 = base + 1 < N ? deg[base + 1] : 0;
    int d2 = base + 2 < N ? deg[base + 2] : 0;
    int d3 = base + 3 < N ? deg[base + 3] : 0;
    int tsum = d0 + d1 + d2 + d3;
    sh[tid] = tsum;
    __syncthreads();
    for (int off = 1; off < 256; off <<= 1) {
        int v = 0;
        if (tid >= off) v = sh[tid - off];
        __syncthreads();
        if (tid >= off) sh[tid] += v;
        __syncthreads();
    }
    int excl = sh[tid] - tsum;
    if (base + 0 < N) rowptr[base + 0] = excl;
    if (base + 1 < N) rowptr[base + 1] = excl + d0;
    if (base + 2 < N) rowptr[base + 2] = excl + d0 + d1;
    if (base + 3 < N) rowptr[base + 3] = excl + d0 + d1 + d2;
    if (tid == 255) bsum[blockIdx.x] = sh[255];
}
__global__ void csr_scan2_kernel(int* __restrict__ bsum, int* __restrict__ rowptr,
                                 int nb, int N) {
    if (threadIdx.x == 0 && blockIdx.x == 0) {
        int running = 0;
        for (int b = 0; b < nb; ++b) {
            int t = bsum[b];
            bsum[b] = running;
            running += t;
        }
        rowptr[N] = running;
    }
}
__global__ void csr_scan3_kernel(int* __restrict__ rowptr, int* __restrict__ cursor,
                                 const int* __restrict__ bsum, int N) {
    int tid = threadIdx.x;
    int base = blockIdx.x * 1024 + tid * 4;
    int ofs = bsum[blockIdx.x];
#pragma unroll
    for (int j = 0; j < 4; ++j) {
        if (base + j < N) {
            int v = rowptr[base + j] + ofs;
            rowptr[base + j] = v;
            cursor[base + j] = v;
        }
    }
}
__global__ void csr_scatter_kernel(const int* __restrict__ ei, const float* __restrict__ ea,
                                   int* __restrict__ cursor,
                                   int* __restrict__ csr_src, float* __restrict__ csr_ea,
                                   int E) {
    int e = blockIdx.x * 256 + threadIdx.x;
    if (e >= E) return;
    int s = ei[e], d = ei[E + e];
    int pos = atomicAdd(&cursor[d], 1);
    csr_src[pos] = s;
    *(float2*)(csr_ea + (size_t)pos * 2) = *(const float2*)(ea + (size_t)e * 2);
}

// ---- GAT scores (layer 0): hs(bf16) = h@W via MFMA; asrc/adst = h.(W@a).
__global__ __launch_bounds__(256, 4) void gat_scores_kernel(
        const float* __restrict__ h, const ushort* __restrict__ gfrag,
        const float* __restrict__ va, ushort* __restrict__ hs,
        float* __restrict__ asrc, float* __restrict__ adst, int N) {
    int tid = threadIdx.x;
    int l = tid & 63, wave = tid >> 6;
    int n0 = (blockIdx.x * 4 + wave) * 32;
    if (n0 >= N) return;
    const int row_a = l & 31, kg = (l >> 5) * 8;
    bool valid = (n0 + row_a) < N;
    const float* hrow = h + (size_t)(n0 + row_a) * 64;
    bf16x8 ahi[4], alo[4];
    float ps = 0.f, pd = 0.f;
#pragma unroll
    for (int c = 0; c < 4; ++c) {
        float hv[8];
        if (valid) {
            float4 v0 = *(const float4*)(hrow + c * 16 + kg);
            float4 v1 = *(const float4*)(hrow + c * 16 + kg + 4);
            hv[0] = v0.x; hv[1] = v0.y; hv[2] = v0.z; hv[3] = v0.w;
            hv[4] = v1.x; hv[5] = v1.y; hv[6] = v1.z; hv[7] = v1.w;
        } else {
#pragma unroll
            for (int j = 0; j < 8; ++j) hv[j] = 0.f;
        }
#pragma unroll
        for (int j = 0; j < 8; ++j) {
            ps += hv[j] * va[c * 16 + kg + j];
            pd += hv[j] * va[64 + c * 16 + kg + j];
            ushort hb = bf_rne(hv[j]);
            ahi[c][j] = (short)hb;
            alo[c][j] = (short)bf_rne(hv[j] - bf_dec(hb));
        }
    }
    ps += __shfl_xor(ps, 32, 64);
    pd += __shfl_xor(pd, 32, 64);
    if (l < 32 && valid) { asrc[n0 + l] = ps; adst[n0 + l] = pd; }
#pragma unroll
    for (int cb = 0; cb < 2; ++cb) {
        f32x16 acc = {};
#pragma unroll
        for (int c = 0; c < 4; ++c) {
            const ushort* bp = gfrag + (size_t)(((cb * 4 + c) * 64 + l) * 8);
            bf16x8 bhi = *(const bf16x8*)bp;
            bf16x8 blo = *(const bf16x8*)(bp + 4096);
            acc = __builtin_amdgcn_mfma_f32_32x32x16_bf16(ahi[c], bhi, acc, 0, 0, 0);
            acc = __builtin_amdgcn_mfma_f32_32x32x16_bf16(alo[c], bhi, acc, 0, 0, 0);
            acc = __builtin_amdgcn_mfma_f32_32x32x16_bf16(ahi[c], blo, acc, 0, 0, 0);
        }
#pragma unroll
        for (int r = 0; r < 16; ++r) {
            int row = (r & 3) + 8 * (r >> 2) + 4 * (l >> 5);
            int node = n0 + row;
            if (node < N) hs[(size_t)node * 64 + cb * 32 + (l & 31)] = bf_rne(acc[r]);
        }
    }
}

// ---- Fused per-dst edge kernel: persistent grid-stride (R20-proven).
__global__ void gat_edge_kernel(const int* __restrict__ rowptr,
                                const int* __restrict__ csr_src,
                                const float* __restrict__ csr_ea,
                                const float* __restrict__ asrc,
                                const float* __restrict__ adst,
                                const float* __restrict__ weae,
                                const ushort* __restrict__ hs,
                                const float* __restrict__ bias,
                                float* __restrict__ go,
                                double* __restrict__ stats, int N) {
    int tid = threadIdx.x;
    int lane = tid & 63, wave = tid >> 6;
    int stride = gridDim.x * 4;
    float bl = bias[lane];
    float w0 = weae[0], w1 = weae[1];
    double sAcc = 0.0, ssAcc = 0.0;
    for (int d = blockIdx.x * 4 + wave; d < N; d += stride) {
        float acc = bl;
        int start = rowptr[d], deg = rowptr[d + 1] - start;
        float ad = adst[d];
        if (deg > 0 && deg <= 64) {
            int s = 0;
            float a = -1e30f;
            if (lane < deg) {
                s = csr_src[start + lane];
                float2 eav = *(const float2*)(csr_ea + (size_t)(start + lane) * 2);
                a = asrc[s] + ad + eav.x * w0 + eav.y * w1;
                a = a > 0.f ? a : 0.2f * a;
            }
            float m = a;
            for (int mm = 32; mm; mm >>= 1) m = fmaxf(m, __shfl_xor(m, mm, 64));
            float ex = lane < deg ? __expf(a - m) : 0.f;
            float den = ex;
            for (int mm = 32; mm; mm >>= 1) den += __shfl_xor(den, mm, 64);
            float w = ex * frcp(den + 1e-16f);
            for (int j = 0; j < deg; ++j) {
                int sj = __builtin_amdgcn_readlane(s, j);
                float wj = bcast(w, j);
                acc += wj * bf_dec(hs[(size_t)sj * 64 + lane]);
            }
        } else if (deg > 64) {
            float m = -1e30f;
            for (int c0 = 0; c0 < deg; c0 += 64) {
                float a = -1e30f;
                if (c0 + lane < deg) {
                    int s2 = csr_src[start + c0 + lane];
                    float2 eav = *(const float2*)(csr_ea + (size_t)(start + c0 + lane) * 2);
                    a = asrc[s2] + ad + eav.x * w0 + eav.y * w1;
                    a = a > 0.f ? a : 0.2f * a;
                }
                for (int mm = 32; mm; mm >>= 1) a = fmaxf(a, __shfl_xor(a, mm, 64));
                m = fmaxf(m, a);
            }
            float den = 0.f;
            for (int c0 = 0; c0 < deg; c0 += 64) {
                float a = -1e30f;
                if (c0 + lane < deg) {
                    int s2 = csr_src[start + c0 + lane];
                    float2 eav = *(const float2*)(csr_ea + (size_t)(start + c0 + lane) * 2);
                    a = asrc[s2] + ad + eav.x * w0 + eav.y * w1;
                    a = a > 0.f ? a : 0.2f * a;
                }
                float ex = (c0 + lane < deg) ? __expf(a - m) : 0.f;
                for (int mm = 32; mm; mm >>= 1) ex += __shfl_xor(ex, mm, 64);
                den += ex;
            }
            for (int c0 = 0; c0 < deg; c0 += 64) {
                int s2 = 0;
                float a = -1e30f;
                if (c0 + lane < deg) {
                    s2 = csr_src[start + c0 + lane];
                    float2 eav = *(const float2*)(csr_ea + (size_t)(start + c0 + lane) * 2);
                    a = asrc[s2] + ad + eav.x * w0 + eav.y * w1;
                    a = a > 0.f ? a : 0.2f * a;
                }
                float w = ((c0 + lane < deg) ? __expf(a - m) : 0.f) * frcp(den + 1e-16f);
                int cnt = deg - c0 < 64 ? deg - c0 : 64;
                for (int j = 0; j < cnt; ++j) {
                    int sj = __builtin_amdgcn_readlane(s2, j);
                    float wj = bcast(w, j);
                    acc += wj * bf_dec(hs[(size_t)sj * 64 + lane]);
                }
            }
        }
        go[(size_t)d * 64 + lane] = acc;
        sAcc += (double)acc;
        ssAcc += (double)acc * acc;
    }
    for (int mm = 32; mm; mm >>= 1) { sAcc += __shfl_xor(sAcc, mm, 64); ssAcc += __shfl_xor(ssAcc, mm, 64); }
    __shared__ double sh[8];
    if (lane == 0) { sh[wave * 2] = sAcc; sh[wave * 2 + 1] = ssAcc; }
    __syncthreads();
    if (tid == 0) {
        double ts = 0, tss = 0;
        for (int w2 = 0; w2 < 4; ++w2) { ts += sh[w2 * 2]; tss += sh[w2 * 2 + 1]; }
        double* slot = stats + (blockIdx.x & 63) * 2;
        unsafeAtomicAdd(&slot[0], ts);
        unsafeAtomicAdd(&slot[1], tss);
    }
}

// ---- Fused: LN(graph)+ReLU -> v; fc1acc += v@W_fc1_slice^T (MFMA);
//      and (if do_next) next layer's hs(bf16) = v@W_gat, asrc/adst = v.(W@a).
__global__ __launch_bounds__(256, 4) void ln_apply_kernel(
        const float* __restrict__ go, const double* __restrict__ stats,
        const float* __restrict__ g, const float* __restrict__ b,
        const ushort* __restrict__ ffrag, const ushort* __restrict__ gwnext,
        const float* __restrict__ vanext,
        float* __restrict__ fc1acc, ushort* __restrict__ hs,
        float* __restrict__ asrc, float* __restrict__ adst,
        int N, int do_next) {
    int tid = threadIdx.x;
    int l = tid & 63, wave = tid >> 6;
    double sA = stats[l * 2], sB = stats[l * 2 + 1];
    for (int mm = 32; mm; mm >>= 1) { sA += __shfl_xor(sA, mm, 64); sB += __shfl_xor(sB, mm, 64); }
    double M = (double)N * 64.0;
    double mu = sA / M;
    float mean = (float)mu;
    float var = (float)(sB / M - mu * mu);
    float inv = 1.f / (sqrtf(fmaxf(var, 0.f)) + 1e-5f);
    int n0 = (blockIdx.x * 4 + wave) * 32;
    if (n0 >= N) return;
    const int row_a = l & 31, kg = (l >> 5) * 8;
    bool valid = (n0 + row_a) < N;
    const float* gorow = go + (size_t)(n0 + row_a) * 64;
    bf16x8 ahi[4], alo[4];
    float ps = 0.f, pd = 0.f;
#pragma unroll
    for (int c = 0; c < 4; ++c) {
        int ch0 = c * 16 + kg;
        float4 g0 = *(const float4*)(g + ch0);
        float4 g1 = *(const float4*)(g + ch0 + 4);
        float4 b0 = *(const float4*)(b + ch0);
        float4 b1 = *(const float4*)(b + ch0 + 4);
        float gl[8] = {g0.x, g0.y, g0.z, g0.w, g1.x, g1.y, g1.z, g1.w};
        float bl[8] = {b0.x, b0.y, b0.z, b0.w, b1.x, b1.y, b1.z, b1.w};
        float hv[8];
        if (valid) {
            float4 v0 = *(const float4*)(gorow + ch0);
            float4 v1 = *(const float4*)(gorow + ch0 + 4);
            hv[0] = v0.x; hv[1] = v0.y; hv[2] = v0.z; hv[3] = v0.w;
            hv[4] = v1.x; hv[5] = v1.y; hv[6] = v1.z; hv[7] = v1.w;
        } else {
#pragma unroll
            for (int j = 0; j < 8; ++j) hv[j] = 0.f;
        }
#pragma unroll
        for (int j = 0; j < 8; ++j) {
            float v = fmaxf((hv[j] - mean) * inv * gl[j] + bl[j], 0.f);
            ps += v * vanext[c * 16 + kg + j];
            pd += v * vanext[64 + c * 16 + kg + j];
            ushort hb = bf_rne(v);
            ahi[c][j] = (short)hb;
            alo[c][j] = (short)bf_rne(v - bf_dec(hb));
        }
    }
#pragma unroll
    for (int cb = 0; cb < 2; ++cb) {
        f32x16 acc = {};
#pragma unroll
        for (int c = 0; c < 4; ++c) {
            const ushort* bp = ffrag + (size_t)(((cb * 4 + c) * 64 + l) * 8);
            bf16x8 bhi = *(const bf16x8*)bp;
            bf16x8 blo = *(const bf16x8*)(bp + 4096);
            acc = __builtin_amdgcn_mfma_f32_32x32x16_bf16(ahi[c], bhi, acc, 0, 0, 0);
            acc = __builtin_amdgcn_mfma_f32_32x32x16_bf16(alo[c], bhi, acc, 0, 0, 0);
            acc = __builtin_amdgcn_mfma_f32_32x32x16_bf16(ahi[c], blo, acc, 0, 0, 0);
        }
#pragma unroll
        for (int r = 0; r < 16; ++r) {
            int row = (r & 3) + 8 * (r >> 2) + 4 * (l >> 5);
            int node = n0 + row;
            if (node < N) fc1acc[(size_t)node * 64 + cb * 32 + (l & 31)] += acc[r];
        }
    }
    if (do_next) {
        ps += __shfl_xor(ps, 32, 64);
        pd += __shfl_xor(pd, 32, 64);
        if (l < 32 && valid) { asrc[n0 + l] = ps; adst[n0 + l] = pd; }
#pragma unroll
        for (int cb = 0; cb < 2; ++cb) {
            f32x16 acc = {};
#pragma unroll
            for (int c = 0; c < 4; ++c) {
                const ushort* bp = gwnext + (size_t)(((cb * 4 + c) * 64 + l) * 8);
                bf16x8 bhi = *(const bf16x8*)bp;
                bf16x8 blo = *(const bf16x8*)(bp + 4096);
                acc = __builtin_amdgcn_mfma_f32_32x32x16_bf16(ahi[c], bhi, acc, 0, 0, 0);
                acc = __builtin_amdgcn_mfma_f32_32x32x16_bf16(alo[c], bhi, acc, 0, 0, 0);
                acc = __builtin_amdgcn_mfma_f32_32x32x16_bf16(ahi[c], blo, acc, 0, 0, 0);
            }
#pragma unroll
            for (int r = 0; r < 16; ++r) {
                int row = (r & 3) + 8 * (r >> 2) + 4 * (l >> 5);
                int node = n0 + row;
                if (node < N) hs[(size_t)node * 64 + cb * 32 + (l & 31)] = bf_rne(acc[r]);
            }
        }
    }
}

__global__ void head_kernel(const float* __restrict__ fc1acc, const float* __restrict__ b1,
                            const float* __restrict__ W2, const float* __restrict__ b2,
                            float* __restrict__ out, int N) {
    int lane = threadIdx.x & 63, wave = threadIdx.x >> 6;
    int n = blockIdx.x * 4 + wave;
    if (n >= N) return;
    float v = fmaxf(fc1acc[n * 64 + lane] + b1[lane], 0.f);
    float r0 = v * W2[lane];
    float r1 = v * W2[64 + lane];
    for (int m = 32; m; m >>= 1) { r0 += __shfl_xor(r0, m, 64); r1 += __shfl_xor(r1, m, 64); }
    if (lane == 0) { out[n * 2 + 0] = r0 + b2[0]; out[n * 2 + 1] = r1 + b2[1]; }
}

extern "C" void kernel_launch(void* const* d_in, const int* in_sizes, int n_in,
                              void* d_out, int out_size, void* d_ws, size_t ws_size,
                              hipStream_t stream) {
    const float* x        = (const float*)d_in[0];
    const int*   ei       = (const int*)d_in[1];
    const float* ea       = (const float*)d_in[2];
    const float* W_ih     = (const float*)d_in[3];
    const float* W_hh     = (const float*)d_in[4];
    const float* b_ih     = (const float*)d_in[5];
    const float* b_hh     = (const float*)d_in[6];
    const float* W_gat    = (const float*)d_in[7];
    const float* att_src  = (const float*)d_in[8];
    const float* att_dst  = (const float*)d_in[9];
    const float* W_edge   = (const float*)d_in[10];
    const float* att_edge = (const float*)d_in[11];
    const float* b_gat    = (const float*)d_in[12];
    const float* ln_g     = (const float*)d_in[13];
    const float* ln_b     = (const float*)d_in[14];
    const float* W_fc1    = (const float*)d_in[15];
    const float* b_fc1    = (const float*)d_in[16];
    const float* W_fc2    = (const float*)d_in[17];
    const float* b_fc2    = (const float*)d_in[18];
    float* out = (float*)d_out;

    int N = in_sizes[0] / (T_STEPS * 2);
    int E = in_sizes[1] / 2;
    size_t N64 = (size_t)N * 64;

    float* ws   = (float*)d_ws;
    float* h    = ws;
    ushort* hs  = (ushort*)(h + N64);               // N64 bf16
    float* go   = (float*)(hs + N64);
    float* fc1  = go + N64;
    float* asrc = fc1 + N64;
    float* adst = asrc + N;
    float* va_all   = adst + N;                     // 640
    float* weae_all = va_all + 640;                 // 10
    double* stats = (double*)(((uintptr_t)(weae_all + 10) + 15) & ~(uintptr_t)15);  // 640
    ushort* wfrag = (ushort*)(stats + 640);         // 24576
    ushort* gw    = wfrag + 24576;                  // 40960
    ushort* gf    = gw + 40960;                     // 40960
    int* deg     = (int*)(gf + 40960);
    int* rowptr  = deg + N;                          // N+1
    int* cursor  = rowptr + N + 1;
    int* bsum    = cursor + N;                       // <=128
    int* csr_src = bsum + 128;                       // E
    float* csr_ea = (float*)(((uintptr_t)(csr_src + E) + 15) & ~(uintptr_t)15);  // 2E

    int nb = (N + 1023) / 1024;
    int tiles = (N + 31) / 32;
    int lstm_grid = (tiles + 15) / 16;
    if (lstm_grid < 256) lstm_grid = 256;   // spread over all CUs; tile = wave*grid + blk

    lstm_prep_kernel<<<15, 256, 0, stream>>>(W_hh, W_ih, b_ih, b_hh, wfrag, stats);
    prep2_kernel<<<23, 256, 0, stream>>>(W_gat, att_src, att_dst, W_edge, att_edge,
                                         W_fc1, gw, gf, va_all, weae_all);
    lstm_kernel<<<lstm_grid, 1024, 114688, stream>>>(x, wfrag, h, fc1, N);

    csr_zero_kernel<<<(N + 255) / 256, 256, 0, stream>>>(deg, N);
    csr_hist_kernel<<<(E + 255) / 256, 256, 0, stream>>>(ei, deg, E);
    csr_scan1_kernel<<<nb, 256, 0, stream>>>(deg, rowptr, bsum, N);
    csr_scan2_kernel<<<1, 64, 0, stream>>>(bsum, rowptr, nb, N);
    csr_scan3_kernel<<<nb, 256, 0, stream>>>(rowptr, cursor, bsum, N);
    csr_scatter_kernel<<<(E + 255) / 256, 256, 0, stream>>>(ei, ea, cursor, csr_src, csr_ea, E);

    gat_scores_kernel<<<(N + 127) / 128, 256, 0, stream>>>(h, gw, va_all, hs, asrc, adst, N);

    for (int l = 0; l < 5; ++l) {
        int nl = l + 1 < 5 ? l + 1 : 4;
        gat_edge_kernel<<<2048, 256, 0, stream>>>(
            rowptr, csr_src, csr_ea, asrc, adst, weae_all + l * 2, hs, b_gat + l * 64,
            go, stats + l * 128, N);
        ln_apply_kernel<<<(N + 127) / 128, 256, 0, stream>>>(
            go, stats + l * 128, ln_g + l * 64, ln_b + l * 64, gf + l * 8192,
            gw + nl * 8192, va_all + nl * 128, fc1, hs, asrc, adst, N, l < 4 ? 1 : 0);
    }
    head_kernel<<<(N + 3) / 4, 256, 0, stream>>>(fc1, b_fc1, W_fc2, b_fc2, out, N);
}